// Round 1
// baseline (743.606 us; speedup 1.0000x reference)
//
#include <hip/hip_runtime.h>
#include <hip/hip_fp16.h>

typedef _Float16 half_t;
typedef _Float16 half2_t __attribute__((ext_vector_type(2)));
typedef _Float16 f16x8 __attribute__((ext_vector_type(8)));
typedef float f32x4 __attribute__((ext_vector_type(4)));
typedef unsigned int u32;

// B=256, T=500, I=H=256, O=128, M=B*T=128000
#define MROWS 128000
#define KDIM 256

__device__ __forceinline__ float fdot2u(u32 w, u32 h, float acc) {
    return __builtin_amdgcn_fdot2(__builtin_bit_cast(half2_t, w),
                                  __builtin_bit_cast(half2_t, h), acc, false);
}

// ---------------- prep: convert weights to f16 layouts, fold biases ----------
__global__ __launch_bounds__(256) void prep_kernel(
    const float* __restrict__ Wih0, const float* __restrict__ Whh0,
    const float* __restrict__ bih0, const float* __restrict__ bhh0,
    const float* __restrict__ Wih1, const float* __restrict__ Whh1,
    const float* __restrict__ bih1, const float* __restrict__ bhh1,
    const float* __restrict__ fcW,  const float* __restrict__ fcb,
    half_t* __restrict__ Wh0, half_t* __restrict__ Wh1, half_t* __restrict__ fcWh,
    u32* __restrict__ Wt0, u32* __restrict__ Wt1,
    float* __restrict__ bias0, float* __restrict__ bias1, float* __restrict__ bias2)
{
    int e = blockIdx.x * 256 + threadIdx.x;   // 0..65535
    Wh0[e] = (half_t)Wih0[e];
    Wh1[e] = (half_t)Wih1[e];
    if (e < 32768) {
        fcWh[e] = (half_t)fcW[e];
        int k2 = e >> 8, j = e & 255;
        { half2_t p; p.x = (half_t)Whh0[j*256 + 2*k2]; p.y = (half_t)Whh0[j*256 + 2*k2 + 1];
          Wt0[e] = __builtin_bit_cast(u32, p); }
        { half2_t p; p.x = (half_t)Whh1[j*256 + 2*k2]; p.y = (half_t)Whh1[j*256 + 2*k2 + 1];
          Wt1[e] = __builtin_bit_cast(u32, p); }
    }
    if (e < 256) { bias0[e] = bih0[e] + bhh0[e]; bias1[e] = bih1[e] + bhh1[e]; }
    if (e < 128) { bias2[e] = fcb[e]; }
}

// ---------------- GEMM: C[M,NT] = A[M,256] * W[NT,256]^T + bias (f16 MFMA) ---
template<typename AT, typename OT, int NT, bool SIG>
__global__ __launch_bounds__(512) void gemm_bt(
    const AT* __restrict__ A, const half_t* __restrict__ W,
    const float* __restrict__ bias, OT* __restrict__ C)
{
    constexpr int K = KDIM;
    __shared__ __align__(16) half_t As[128][72];   // +8 pad: 2-way bank alias only
    __shared__ __align__(16) half_t Ws[NT][72];
    __shared__ float bs[NT];
    const int tid  = threadIdx.x;
    const int row0 = blockIdx.x * 128;
    if (tid < NT) bs[tid] = bias[tid];
    constexpr int NFRAG = NT / 64;                 // 4 (NT=256) or 2 (NT=128)
    f32x4 acc[4][NFRAG] = {};
    const int lane = tid & 63;
    const int wid  = tid >> 6;                     // 8 waves: 2 (rows) x 4 (cols)
    const int wr = wid >> 2, wc = wid & 3;

    for (int kt = 0; kt < 4; ++kt) {
        const int k0 = kt * 64;
        if constexpr (sizeof(AT) == 4) {           // fp32 A -> convert to f16
            #pragma unroll
            for (int p = 0; p < 4; ++p) {
                int idx = p * 512 + tid; int r = idx >> 4; int c4 = (idx & 15) * 4;
                const float4 v = *(const float4*)(A + (size_t)(row0 + r) * K + k0 + c4);
                half2_t h01; h01.x = (half_t)v.x; h01.y = (half_t)v.y;
                half2_t h23; h23.x = (half_t)v.z; h23.y = (half_t)v.w;
                *(half2_t*)&As[r][c4]     = h01;
                *(half2_t*)&As[r][c4 + 2] = h23;
            }
        } else {                                   // f16 A
            #pragma unroll
            for (int p = 0; p < 2; ++p) {
                int idx = p * 512 + tid; int r = idx >> 3; int c8 = (idx & 7) * 8;
                uint4 v = *(const uint4*)(A + (size_t)(row0 + r) * K + k0 + c8);
                *(uint4*)&As[r][c8] = v;
            }
        }
        #pragma unroll
        for (int p = 0; p < NT / 64; ++p) {        // stage W tile (f16)
            int idx = p * 512 + tid; int r = idx >> 3; int c8 = (idx & 7) * 8;
            uint4 v = *(const uint4*)(W + (size_t)r * K + k0 + c8);
            *(uint4*)&Ws[r][c8] = v;
        }
        __syncthreads();
        #pragma unroll
        for (int kkh = 0; kkh < 2; ++kkh) {
            const int kk = kkh * 32 + ((lane >> 4) * 8);
            f16x8 af[4], bf[NFRAG];
            #pragma unroll
            for (int m = 0; m < 4; ++m)
                af[m] = *(const f16x8*)&As[wr * 64 + m * 16 + (lane & 15)][kk];
            #pragma unroll
            for (int n = 0; n < NFRAG; ++n)
                bf[n] = *(const f16x8*)&Ws[wc * (NT / 4) + n * 16 + (lane & 15)][kk];
            #pragma unroll
            for (int m = 0; m < 4; ++m)
                #pragma unroll
                for (int n = 0; n < NFRAG; ++n)
                    acc[m][n] = __builtin_amdgcn_mfma_f32_16x16x32_f16(af[m], bf[n], acc[m][n], 0, 0, 0);
        }
        __syncthreads();
    }
    #pragma unroll
    for (int m = 0; m < 4; ++m)
        #pragma unroll
        for (int n = 0; n < NFRAG; ++n)
            #pragma unroll
            for (int jj = 0; jj < 4; ++jj) {
                int rl = wr * 64 + m * 16 + ((lane >> 4) * 4) + jj;
                int cl = wc * (NT / 4) + n * 16 + (lane & 15);
                float v = acc[m][n][jj] + bs[cl];
                if constexpr (SIG) v = 1.0f / (1.0f + __expf(-v));
                C[(size_t)(row0 + rl) * NT + cl] = (OT)v;
            }
}

// ---------------- recurrent scan: h_t = tanh(xp_t + W_hh h_{t-1}) ------------
// One block per batch row. W_hh in 128 VGPRs (f16x2), h broadcast via LDS.
// T=500 = 25 chunks x 20 steps; xp chunk-staged, h chunk-flushed.
__global__ __launch_bounds__(256, 1) void rnn_scan(
    const u32* __restrict__ Wt2,        // [128][256] packed f16x2, [k2][j]
    const half_t* __restrict__ xp,      // [256][500][256]
    half_t* __restrict__ hout)          // [256][500][256]
{
    __shared__ __align__(16) half_t hist[20][256];
    __shared__ __align__(16) half_t xpl[20][256];
    const int b = blockIdx.x;
    const int j = threadIdx.x;
    u32 w[128];
    #pragma unroll
    for (int k2 = 0; k2 < 128; ++k2) w[k2] = Wt2[k2 * 256 + j];   // coalesced
    const size_t base = (size_t)b * 500 * 256;
    const uint2* xg = (const uint2*)(xp + base);   // chunk = 1280 uint2
    uint2* hg = (uint2*)(hout + base);

    hist[19][j] = (half_t)0.f;                     // h(-1) = 0
    uint2 xr[5];
    #pragma unroll
    for (int p = 0; p < 5; ++p) ((uint2*)&xpl[0][0])[p * 256 + j] = xg[p * 256 + j];
    #pragma unroll
    for (int p = 0; p < 5; ++p) xr[p] = xg[1280 + p * 256 + j];    // prefetch chunk 1
    __syncthreads();

    for (int ch = 0; ch < 25; ++ch) {
        for (int tc = 0; tc < 20; ++tc) {
            const int prev = (tc == 0) ? 19 : tc - 1;
            const uint4* hrow = (const uint4*)&hist[prev][0];      // broadcast reads
            float a0 = (float)xpl[tc][j], a1 = 0.f, a2 = 0.f, a3 = 0.f;
            uint4 hb[8];
            #pragma unroll
            for (int i = 0; i < 8; ++i) hb[i] = hrow[i];           // depth-8 pipeline
            #pragma unroll
            for (int g = 0; g < 32; ++g) {
                uint4 hv = hb[g & 7];
                if (g + 8 < 32) hb[g & 7] = hrow[g + 8];
                a0 = fdot2u(w[4 * g + 0], hv.x, a0);
                a1 = fdot2u(w[4 * g + 1], hv.y, a1);
                a2 = fdot2u(w[4 * g + 2], hv.z, a2);
                a3 = fdot2u(w[4 * g + 3], hv.w, a3);
            }
            float h = tanhf((a0 + a1) + (a2 + a3));
            hist[tc][j] = (half_t)h;
            __syncthreads();                       // single barrier per step
        }
        // chunk boundary: flush h history, rotate xp staging
        #pragma unroll
        for (int p = 0; p < 5; ++p)
            hg[(size_t)ch * 1280 + p * 256 + j] = ((const uint2*)&hist[0][0])[p * 256 + j];
        if (ch + 1 < 25) {
            #pragma unroll
            for (int p = 0; p < 5; ++p) ((uint2*)&xpl[0][0])[p * 256 + j] = xr[p];
            if (ch + 2 < 25) {
                #pragma unroll
                for (int p = 0; p < 5; ++p) xr[p] = xg[(size_t)(ch + 2) * 1280 + p * 256 + j];
            }
            __syncthreads();
        }
    }
}

// ---------------- launch ----------------
extern "C" void kernel_launch(void* const* d_in, const int* in_sizes, int n_in,
                              void* d_out, int out_size, void* d_ws, size_t ws_size,
                              hipStream_t stream) {
    const float* x    = (const float*)d_in[0];
    const float* Wih0 = (const float*)d_in[1];
    const float* Whh0 = (const float*)d_in[2];
    const float* bih0 = (const float*)d_in[3];
    const float* bhh0 = (const float*)d_in[4];
    const float* Wih1 = (const float*)d_in[5];
    const float* Whh1 = (const float*)d_in[6];
    const float* bih1 = (const float*)d_in[7];
    const float* bhh1 = (const float*)d_in[8];
    const float* fcW  = (const float*)d_in[9];
    const float* fcb  = (const float*)d_in[10];

    char* ws = (char*)d_ws;
    size_t off = 0;
    auto alloc = [&](size_t bytes) { void* p = ws + off; off += (bytes + 255) & ~(size_t)255; return p; };
    half_t* xp_buf = (half_t*)alloc((size_t)MROWS * 256 * 2);  // 65.5 MB
    half_t* h_buf  = (half_t*)alloc((size_t)MROWS * 256 * 2);  // 65.5 MB
    half_t* Wh0    = (half_t*)alloc(65536 * 2);
    half_t* Wh1    = (half_t*)alloc(65536 * 2);
    half_t* fcWh   = (half_t*)alloc(32768 * 2);
    u32*    Wt0    = (u32*)alloc(32768 * 4);
    u32*    Wt1    = (u32*)alloc(32768 * 4);
    float*  bias0  = (float*)alloc(256 * 4);
    float*  bias1  = (float*)alloc(256 * 4);
    float*  bias2  = (float*)alloc(128 * 4);

    prep_kernel<<<256, 256, 0, stream>>>(Wih0, Whh0, bih0, bhh0, Wih1, Whh1, bih1, bhh1,
                                         fcW, fcb, Wh0, Wh1, fcWh, Wt0, Wt1, bias0, bias1, bias2);
    // layer 0 input projection (fp32 x -> f16 xp)
    gemm_bt<float, half_t, 256, false><<<1000, 512, 0, stream>>>(x, Wh0, bias0, xp_buf);
    // layer 0 scan
    rnn_scan<<<256, 256, 0, stream>>>(Wt0, xp_buf, h_buf);
    // layer 1 input projection (f16 h1 -> f16 xp), reuses xp buffer
    gemm_bt<half_t, half_t, 256, false><<<1000, 512, 0, stream>>>(h_buf, Wh1, bias1, xp_buf);
    // layer 1 scan (overwrites h buffer)
    rnn_scan<<<256, 256, 0, stream>>>(Wt1, xp_buf, h_buf);
    // FC head + sigmoid -> fp32 out
    gemm_bt<half_t, float, 128, true><<<1000, 512, 0, stream>>>(h_buf, fcWh, bias2, (float*)d_out);
}